// Round 1
// baseline (983.242 us; speedup 1.0000x reference)
//
#include <hip/hip_runtime.h>
#include <hip/hip_bf16.h>
#include <math.h>

#define BB 2
#define LL 2048
#define DD 256
#define NT (BB*LL)      // 4096 tokens
#define HCOLS 896       // ke(256) qe(256) lke(256) gate(128)
#define NCOLS 1152      // HCOLS + v(256)
#define FDIM 80         // 32 bank + 8 joint + 32 pos + 8 pad
#define FPAD 84         // LDS row pad (mod 32 = 20 -> 4-way worst case)
#define PI_F 3.14159265358979323846f

__device__ __forceinline__ float gelu_erf(float v) {
    return 0.5f * v * (1.0f + erff(v * 0.70710678118654752440f));
}
__device__ __forceinline__ float sigmoidf_(float v) {
    return 1.0f / (1.0f + expf(-v));
}

// ---------------- K1: first layers: H = gelu(X@W1+b1) for ke/qe/lke/gate, V = X@v_w+v_b
__global__ __launch_bounds__(256) void k1_first(
    const float* __restrict__ x,
    const float* __restrict__ ke_w1, const float* __restrict__ ke_b1,
    const float* __restrict__ qe_w1, const float* __restrict__ qe_b1,
    const float* __restrict__ lke_w1, const float* __restrict__ lke_b1,
    const float* __restrict__ gate_w1, const float* __restrict__ gate_b1,
    const float* __restrict__ v_w, const float* __restrict__ v_b,
    float* __restrict__ H, float* __restrict__ V)
{
    __shared__ float xs[8][DD];
    const int tid = threadIdx.x;
    const int t0 = blockIdx.x * 8;
    for (int i = tid; i < 8 * DD; i += 256)
        xs[i >> 8][i & 255] = x[t0 * DD + i];
    __syncthreads();

    const float* ptr[5];
    int ldw[5];
    bool valid[5];
    #pragma unroll
    for (int i = 0; i < 5; ++i) {
        int c = tid + 256 * i;
        valid[i] = (c < NCOLS);
        const float* bp; int ld = 256;
        if (c < 256)       { bp = ke_w1 + c; }
        else if (c < 512)  { bp = qe_w1 + (c - 256); }
        else if (c < 768)  { bp = lke_w1 + (c - 512); }
        else if (c < 896)  { bp = gate_w1 + (c - 768); ld = 128; }
        else if (c < 1152) { bp = v_w + (c - 896); }
        else               { bp = v_w; }  // dummy valid memory, result unused
        ptr[i] = bp; ldw[i] = ld;
    }

    float acc[5][8];
    #pragma unroll
    for (int i = 0; i < 5; ++i)
        #pragma unroll
        for (int t = 0; t < 8; ++t) acc[i][t] = 0.0f;

    for (int k = 0; k < DD; ++k) {
        float w[5];
        #pragma unroll
        for (int i = 0; i < 5; ++i) { w[i] = *ptr[i]; ptr[i] += ldw[i]; }
        #pragma unroll
        for (int t = 0; t < 8; ++t) {
            float xv = xs[t][k];
            #pragma unroll
            for (int i = 0; i < 5; ++i) acc[i][t] += w[i] * xv;
        }
    }

    #pragma unroll
    for (int i = 0; i < 5; ++i) {
        int c = tid + 256 * i;
        if (!valid[i]) continue;
        float bia;
        if (c < 256)      bia = ke_b1[c];
        else if (c < 512) bia = qe_b1[c - 256];
        else if (c < 768) bia = lke_b1[c - 512];
        else if (c < 896) bia = gate_b1[c - 768];
        else              bia = v_b[c - 896];
        #pragma unroll
        for (int t = 0; t < 8; ++t) {
            float v = acc[i][t] + bia;
            int tok = t0 + t;
            if (c < 896) H[tok * HCOLS + c] = gelu_erf(v);
            else         V[tok * DD + (c - 896)] = v;
        }
    }
}

// ---------------- K2: second layers -> phases -> feature vectors
__global__ __launch_bounds__(256) void k2_second(
    const float* __restrict__ H,
    const float* __restrict__ ke_w2, const float* __restrict__ ke_b2,
    const float* __restrict__ qe_w2, const float* __restrict__ qe_b2,
    const float* __restrict__ lke_w2, const float* __restrict__ lke_b2,
    const float* __restrict__ gate_w2, const float* __restrict__ gate_b2,
    const float* __restrict__ set_weights, const float* __restrict__ pos_weight,
    const float* __restrict__ ltm_weight, const float* __restrict__ ltm_count,
    const float* __restrict__ pos_freqs,
    float* __restrict__ Fk, float* __restrict__ Fq, float* __restrict__ Fql)
{
    __shared__ float hs[4][HCOLS];
    __shared__ float ph[4][49];   // 0..15 phi_k, 16..31 phi_q, 32..47 phi_ltm, 48 gate
    const int tid = threadIdx.x;
    const int w = tid >> 6;
    const int lane = tid & 63;
    const int t = blockIdx.x * 4 + w;

    for (int i = lane; i < HCOLS; i += 64) hs[w][i] = H[t * HCOLS + i];
    __syncthreads();

    float val = 0.0f;
    if (lane < 16) {
        float a = ke_b2[lane];
        for (int k = 0; k < 256; ++k) a += hs[w][k] * ke_w2[k * 16 + lane];
        val = tanhf(a) * PI_F;
    } else if (lane < 32) {
        int o = lane - 16;
        float a = qe_b2[o];
        for (int k = 0; k < 256; ++k) a += hs[w][256 + k] * qe_w2[k * 16 + o];
        val = tanhf(a) * PI_F;
    } else if (lane < 48) {
        int o = lane - 32;
        float a = lke_b2[o];
        for (int k = 0; k < 256; ++k) a += hs[w][512 + k] * lke_w2[k * 16 + o];
        val = tanhf(a) * PI_F;
    } else if (lane == 48) {
        float a = gate_b2[0];
        for (int k = 0; k < 128; ++k) a += hs[w][768 + k] * gate_w2[k];
        val = sigmoidf_(a);
    }
    if (lane < 49) ph[w][lane] = val;
    __syncthreads();

    float sw[4];
    {
        float s0 = set_weights[0], s1 = set_weights[1], s2 = set_weights[2], s3 = set_weights[3];
        float mx = fmaxf(fmaxf(s0, s1), fmaxf(s2, s3));
        float e0 = expf(s0 - mx), e1 = expf(s1 - mx), e2 = expf(s2 - mx), e3 = expf(s3 - mx);
        float inv = 1.0f / (e0 + e1 + e2 + e3);
        sw[0] = e0 * inv; sw[1] = e1 * inv; sw[2] = e2 * inv; sw[3] = e3 * inv;
    }
    const float g = ph[w][48];
    const float aq = g * 0.2f;                                  // gate / (N_SETS+1)
    const float apos = (1.0f - g) * sigmoidf_(pos_weight[0]);
    const float altm = sigmoidf_(ltm_weight[0]) / sqrtf(fmaxf(ltm_count[0], 1.0f) * 16.0f);
    const int l = t & (LL - 1);
    float* fkr  = Fk  + t * FDIM;
    float* fqr  = Fq  + t * FDIM;
    float* fqlr = Fql + t * 32;

    if (lane < 16) {
        int p = lane;
        float sk, ck; sincosf(ph[w][p], &sk, &ck);
        fkr[2 * p] = ck; fkr[2 * p + 1] = sk;
        float sq, cq; sincosf(ph[w][16 + p], &sq, &cq);
        float wq = aq * sw[p >> 2];
        fqr[2 * p] = wq * cq; fqr[2 * p + 1] = wq * sq;
        float sl, cl; sincosf(ph[w][32 + p], &sl, &cl);
        fqlr[2 * p] = altm * cl; fqlr[2 * p + 1] = altm * sl;
        float th = (float)l * pos_freqs[p] * (2.0f * PI_F);
        float sp, cp; sincosf(th, &sp, &cp);
        fkr[40 + 2 * p] = cp; fkr[41 + 2 * p] = sp;
        fqr[40 + 2 * p] = apos * cp; fqr[41 + 2 * p] = apos * sp;
    } else if (lane < 20) {
        int p = lane - 16;
        float pjk = ph[w][p] + ph[w][p + 4] + ph[w][p + 8] + ph[w][p + 12];
        float pjq = ph[w][16 + p] + ph[w][20 + p] + ph[w][24 + p] + ph[w][28 + p];
        float sjk, cjk; sincosf(pjk, &sjk, &cjk);
        float sjq, cjq; sincosf(pjq, &sjq, &cjq);
        fkr[32 + 2 * p] = cjk; fkr[33 + 2 * p] = sjk;
        fqr[32 + 2 * p] = aq * cjq; fqr[33 + 2 * p] = aq * sjq;
    } else if (lane < 24) {
        int p = lane - 20;
        fkr[72 + 2 * p] = 0.0f; fkr[73 + 2 * p] = 0.0f;
        fqr[72 + 2 * p] = 0.0f; fqr[73 + 2 * p] = 0.0f;
    }
}

// ---------------- K3: exclusive scan of joint-key phasors -> write gate -> scale Fk[0..39]
__global__ __launch_bounds__(512) void k3_scan(
    float* __restrict__ Fk,
    const float* __restrict__ resonance_scale, const float* __restrict__ resonance_threshold,
    const float* __restrict__ surprise_scale, const float* __restrict__ surprise_bias)
{
    __shared__ float km[8][LL];
    const int b = blockIdx.x;
    const int tid = threadIdx.x;
    const int w = tid >> 6;     // series: 32 + w in Fk dims (2p+comp)
    const int lane = tid & 63;
    {
        float v[32];
        float s = 0.0f;
        const float* src = Fk + (size_t)(b * LL) * FDIM + 32 + w;
        int l0 = lane * 32;
        #pragma unroll 4
        for (int i = 0; i < 32; ++i) { v[i] = src[(size_t)(l0 + i) * FDIM]; s += v[i]; }
        float local = s;
        #pragma unroll
        for (int off = 1; off < 64; off <<= 1) {
            float n = __shfl_up(s, off);
            if (lane >= off) s += n;
        }
        float run = s - local;   // exclusive base
        #pragma unroll 4
        for (int i = 0; i < 32; ++i) { km[w][l0 + i] = run; run += v[i]; }
    }
    __syncthreads();
    const float sc  = fminf(fmaxf(resonance_scale[0], 1.0f), 20.0f);
    const float th  = fminf(fmaxf(resonance_threshold[0], 0.1f), 0.9f);
    const float ssc = surprise_scale[0];
    const float sbi = surprise_bias[0];
    for (int q = 0; q < 4; ++q) {
        int l = tid + 512 * q;
        float rm = 0.0f;
        #pragma unroll
        for (int p = 0; p < 4; ++p) {
            float re = km[2 * p][l], im = km[2 * p + 1][l];
            rm += sqrtf(re * re + im * im);
        }
        rm *= 0.25f;
        float nr = rm / sqrtf(fmaxf((float)l, 1.0f));
        float sur = 0.5f * (1.0f - tanhf(sc * (nr - th)));
        float wg = sigmoidf_(ssc * (sur - 0.5f) + sbi);
        float4* row = reinterpret_cast<float4*>(Fk + (size_t)(b * LL + l) * FDIM);
        #pragma unroll
        for (int j = 0; j < 10; ++j) {   // dims 0..39 (bank+joint); pos dims untouched
            float4 vv = row[j];
            vv.x *= wg; vv.y *= wg; vv.z *= wg; vv.w *= wg;
            row[j] = vv;
        }
    }
}

// ---------------- K4: causal flash  out = (Fq . Fk^T, masked) @ V  + LTM epilogue
__global__ __launch_bounds__(256) void k4_flash(
    const float* __restrict__ Fq, const float* __restrict__ Fk,
    const float* __restrict__ Fql, const float* __restrict__ V,
    const float* __restrict__ ltm_mem, float* __restrict__ Tot)
{
    __shared__ __align__(16) float fq[32][FPAD];
    __shared__ __align__(16) float fk[32][FPAD];
    __shared__ __align__(16) float vs[32][DD];
    __shared__ __align__(16) float ssb[32][32];
    const int tid = threadIdx.x;
    const int b = blockIdx.y;
    const int r0 = blockIdx.x * 32;
    for (int i = tid; i < 32 * FDIM; i += 256) {
        int r = i / FDIM, c = i - r * FDIM;
        fq[r][c] = Fq[(size_t)(b * LL + r0 + r) * FDIM + c];
    }
    float acc[32];
    #pragma unroll
    for (int i = 0; i < 32; ++i) acc[i] = 0.0f;
    const int d = tid;

    for (int j0 = 0; j0 <= r0; j0 += 32) {
        __syncthreads();
        for (int i = tid; i < 32 * FDIM; i += 256) {
            int r = i / FDIM, c = i - r * FDIM;
            fk[r][c] = Fk[(size_t)(b * LL + j0 + r) * FDIM + c];
        }
        for (int i = tid; i < 32 * (DD / 4); i += 256) {
            int r = i >> 6, c4 = i & 63;
            reinterpret_cast<float4*>(&vs[r][0])[c4] =
                reinterpret_cast<const float4*>(V + (size_t)(b * LL + j0 + r) * DD)[c4];
        }
        __syncthreads();
        #pragma unroll
        for (int q = 0; q < 4; ++q) {
            int idx = tid + 256 * q;
            int i_ = idx >> 5, j_ = idx & 31;
            float sv = 0.0f;
            if (r0 + i_ >= j0 + j_) {
                #pragma unroll
                for (int c = 0; c < FDIM; c += 4) {
                    float4 a  = *reinterpret_cast<const float4*>(&fq[i_][c]);
                    float4 bb = *reinterpret_cast<const float4*>(&fk[j_][c]);
                    sv += a.x * bb.x + a.y * bb.y + a.z * bb.z + a.w * bb.w;
                }
            }
            ssb[i_][j_] = sv;
        }
        __syncthreads();
        #pragma unroll
        for (int j4 = 0; j4 < 8; ++j4) {
            float v0 = vs[4 * j4 + 0][d], v1 = vs[4 * j4 + 1][d];
            float v2 = vs[4 * j4 + 2][d], v3 = vs[4 * j4 + 3][d];
            #pragma unroll
            for (int i = 0; i < 32; ++i) {
                float4 s4 = *reinterpret_cast<const float4*>(&ssb[i][4 * j4]);
                acc[i] += s4.x * v0 + s4.y * v1 + s4.z * v2 + s4.w * v3;
            }
        }
    }

    // LTM epilogue: acc[i] += sum_p Fql[2p]*Mre[p][d] + Fql[2p+1]*Mim[p][d]
    float mre[16], mim[16];
    #pragma unroll
    for (int p = 0; p < 16; ++p) {
        mre[p] = ltm_mem[(size_t)(p * DD + d) * 2];
        mim[p] = ltm_mem[(size_t)(p * DD + d) * 2 + 1];
    }
    __syncthreads();
    for (int i = tid; i < 32 * 32; i += 256) {
        int r = i >> 5, c = i & 31;
        ssb[r][c] = Fql[(size_t)(b * LL + r0 + r) * 32 + c];
    }
    __syncthreads();
    #pragma unroll
    for (int i = 0; i < 32; ++i) {
        float a = 0.0f;
        #pragma unroll
        for (int p = 0; p < 16; ++p)
            a += ssb[i][2 * p] * mre[p] + ssb[i][2 * p + 1] * mim[p];
        acc[i] += a;
        Tot[(size_t)(b * LL + r0 + i) * DD + d] = acc[i];
    }
}

// ---------------- K5: LayerNorm + output projection
__global__ __launch_bounds__(256) void k5_out(
    const float* __restrict__ Tot,
    const float* __restrict__ gln, const float* __restrict__ bln,
    const float* __restrict__ out_w, const float* __restrict__ out_b,
    float* __restrict__ out)
{
    __shared__ float hsn[8][DD];
    const int tid = threadIdx.x;
    const int t0 = blockIdx.x * 8;
    const int w = tid >> 6, lane = tid & 63;
    {
        int r = 2 * w + (lane >> 5);
        int l5 = lane & 31;
        float vbuf[8];
        float s = 0.0f, s2 = 0.0f;
        #pragma unroll
        for (int i = 0; i < 8; ++i) {
            float v = Tot[(size_t)(t0 + r) * DD + l5 * 8 + i];
            vbuf[i] = v; s += v; s2 += v * v;
        }
        #pragma unroll
        for (int off = 1; off < 32; off <<= 1) {
            s  += __shfl_xor(s, off);
            s2 += __shfl_xor(s2, off);
        }
        float mu = s * (1.0f / 256.0f);
        float var = s2 * (1.0f / 256.0f) - mu * mu;
        float rstd = rsqrtf(var + 1e-5f);
        #pragma unroll
        for (int i = 0; i < 8; ++i) {
            int k = l5 * 8 + i;
            hsn[r][k] = (vbuf[i] - mu) * rstd * gln[k] + bln[k];
        }
    }
    __syncthreads();
    float acc[8];
    #pragma unroll
    for (int t = 0; t < 8; ++t) acc[t] = 0.0f;
    for (int k = 0; k < DD; ++k) {
        float wv = out_w[k * DD + tid];
        #pragma unroll
        for (int t = 0; t < 8; ++t) acc[t] += hsn[t][k] * wv;
    }
    float ob = out_b[tid];
    #pragma unroll
    for (int t = 0; t < 8; ++t)
        out[(size_t)(t0 + t) * DD + tid] = acc[t] + ob;
}

extern "C" void kernel_launch(void* const* d_in, const int* in_sizes, int n_in,
                              void* d_out, int out_size, void* d_ws, size_t ws_size,
                              hipStream_t stream)
{
    (void)in_sizes; (void)n_in; (void)out_size; (void)ws_size;
    const float* x        = (const float*)d_in[0];
    const float* ke_w1    = (const float*)d_in[1];
    const float* ke_b1    = (const float*)d_in[2];
    const float* ke_w2    = (const float*)d_in[3];
    const float* ke_b2    = (const float*)d_in[4];
    const float* qe_w1    = (const float*)d_in[5];
    const float* qe_b1    = (const float*)d_in[6];
    const float* qe_w2    = (const float*)d_in[7];
    const float* qe_b2    = (const float*)d_in[8];
    const float* v_w      = (const float*)d_in[9];
    const float* v_b      = (const float*)d_in[10];
    const float* out_ln_g = (const float*)d_in[11];
    const float* out_ln_b = (const float*)d_in[12];
    const float* out_w    = (const float*)d_in[13];
    const float* out_b    = (const float*)d_in[14];
    const float* set_weights = (const float*)d_in[15];
    const float* pos_weight  = (const float*)d_in[16];
    const float* gate_w1  = (const float*)d_in[17];
    const float* gate_b1  = (const float*)d_in[18];
    const float* gate_w2  = (const float*)d_in[19];
    const float* gate_b2  = (const float*)d_in[20];
    const float* lke_w1   = (const float*)d_in[21];
    const float* lke_b1   = (const float*)d_in[22];
    const float* lke_w2   = (const float*)d_in[23];
    const float* lke_b2   = (const float*)d_in[24];
    const float* surprise_scale      = (const float*)d_in[25];
    const float* surprise_bias       = (const float*)d_in[26];
    const float* resonance_scale     = (const float*)d_in[27];
    const float* resonance_threshold = (const float*)d_in[28];
    const float* ltm_weight = (const float*)d_in[29];
    const float* pos_freqs  = (const float*)d_in[30];
    const float* ltm_mem    = (const float*)d_in[31];  // complex64 interleaved (16,256)
    const float* ltm_count  = (const float*)d_in[32];

    float* ws  = (float*)d_ws;
    float* H   = ws;                    // NT*896
    float* V   = H   + (size_t)NT * HCOLS;
    float* Fk  = V   + (size_t)NT * DD;
    float* Fq  = Fk  + (size_t)NT * FDIM;
    float* Fql = Fq  + (size_t)NT * FDIM;
    float* Tot = Fql + (size_t)NT * 32;

    k1_first<<<NT / 8, 256, 0, stream>>>(x, ke_w1, ke_b1, qe_w1, qe_b1, lke_w1, lke_b1,
                                         gate_w1, gate_b1, v_w, v_b, H, V);
    k2_second<<<NT / 4, 256, 0, stream>>>(H, ke_w2, ke_b2, qe_w2, qe_b2, lke_w2, lke_b2,
                                          gate_w2, gate_b2, set_weights, pos_weight,
                                          ltm_weight, ltm_count, pos_freqs, Fk, Fq, Fql);
    k3_scan<<<BB, 512, 0, stream>>>(Fk, resonance_scale, resonance_threshold,
                                    surprise_scale, surprise_bias);
    k4_flash<<<dim3(LL / 32, BB), 256, 0, stream>>>(Fq, Fk, Fql, V, ltm_mem, Tot);
    k5_out<<<NT / 8, 256, 0, stream>>>(Tot, out_ln_g, out_ln_b, out_w, out_b, (float*)d_out);
}

// Round 2
// 299.281 us; speedup vs baseline: 3.2853x; 3.2853x over previous
//
#include <hip/hip_runtime.h>
#include <hip/hip_bf16.h>
#include <math.h>

#define BB 2
#define LL 2048
#define DD 256
#define NT (BB*LL)      // 4096 tokens
#define HCOLS 896       // ke(256) qe(256) lke(256) gate(128)
#define NCOLS 1152      // HCOLS + v(256)
#define FDIM 80         // 32 bank + 8 joint + 32 pos + 8 pad
#define FPAD 84         // LDS row pad (84*4=336B, 16B aligned rows)
#define CC 64           // chunk length
#define NC (NT/CC)      // 64 chunks total (chunks never straddle batch: CC | LL)
#define NCB (LL/CC)     // 32 chunks per batch
#define SST (FDIM*DD)   // 20480 floats per chunk state
#define PI_F 3.14159265358979323846f

__device__ __forceinline__ float gelu_erf(float v) {
    return 0.5f * v * (1.0f + erff(v * 0.70710678118654752440f));
}
__device__ __forceinline__ float sigmoidf_(float v) {
    return 1.0f / (1.0f + expf(-v));
}

// ---------------- K1: first layers: H = gelu(X@W1+b1) for ke/qe/lke/gate, V = X@v_w+v_b
__global__ __launch_bounds__(256) void k1_first(
    const float* __restrict__ x,
    const float* __restrict__ ke_w1, const float* __restrict__ ke_b1,
    const float* __restrict__ qe_w1, const float* __restrict__ qe_b1,
    const float* __restrict__ lke_w1, const float* __restrict__ lke_b1,
    const float* __restrict__ gate_w1, const float* __restrict__ gate_b1,
    const float* __restrict__ v_w, const float* __restrict__ v_b,
    float* __restrict__ H, float* __restrict__ V)
{
    __shared__ float xs[8][DD];
    const int tid = threadIdx.x;
    const int t0 = blockIdx.x * 8;
    for (int i = tid; i < 8 * DD; i += 256)
        xs[i >> 8][i & 255] = x[t0 * DD + i];
    __syncthreads();

    const float* ptr[5];
    int ldw[5];
    bool valid[5];
    #pragma unroll
    for (int i = 0; i < 5; ++i) {
        int c = tid + 256 * i;
        valid[i] = (c < NCOLS);
        const float* bp; int ld = 256;
        if (c < 256)       { bp = ke_w1 + c; }
        else if (c < 512)  { bp = qe_w1 + (c - 256); }
        else if (c < 768)  { bp = lke_w1 + (c - 512); }
        else if (c < 896)  { bp = gate_w1 + (c - 768); ld = 128; }
        else if (c < 1152) { bp = v_w + (c - 896); }
        else               { bp = v_w; }  // dummy valid memory, result unused
        ptr[i] = bp; ldw[i] = ld;
    }

    float acc[5][8];
    #pragma unroll
    for (int i = 0; i < 5; ++i)
        #pragma unroll
        for (int t = 0; t < 8; ++t) acc[i][t] = 0.0f;

    for (int k = 0; k < DD; ++k) {
        float w[5];
        #pragma unroll
        for (int i = 0; i < 5; ++i) { w[i] = *ptr[i]; ptr[i] += ldw[i]; }
        #pragma unroll
        for (int t = 0; t < 8; ++t) {
            float xv = xs[t][k];
            #pragma unroll
            for (int i = 0; i < 5; ++i) acc[i][t] += w[i] * xv;
        }
    }

    #pragma unroll
    for (int i = 0; i < 5; ++i) {
        int c = tid + 256 * i;
        if (!valid[i]) continue;
        float bia;
        if (c < 256)      bia = ke_b1[c];
        else if (c < 512) bia = qe_b1[c - 256];
        else if (c < 768) bia = lke_b1[c - 512];
        else if (c < 896) bia = gate_b1[c - 768];
        else              bia = v_b[c - 896];
        #pragma unroll
        for (int t = 0; t < 8; ++t) {
            float v = acc[i][t] + bia;
            int tok = t0 + t;
            if (c < 896) H[tok * HCOLS + c] = gelu_erf(v);
            else         V[tok * DD + (c - 896)] = v;
        }
    }
}

// ---------------- K2: second layers -> phases -> feature vectors
__global__ __launch_bounds__(256) void k2_second(
    const float* __restrict__ H,
    const float* __restrict__ ke_w2, const float* __restrict__ ke_b2,
    const float* __restrict__ qe_w2, const float* __restrict__ qe_b2,
    const float* __restrict__ lke_w2, const float* __restrict__ lke_b2,
    const float* __restrict__ gate_w2, const float* __restrict__ gate_b2,
    const float* __restrict__ set_weights, const float* __restrict__ pos_weight,
    const float* __restrict__ ltm_weight, const float* __restrict__ ltm_count,
    const float* __restrict__ pos_freqs,
    float* __restrict__ Fk, float* __restrict__ Fq, float* __restrict__ Fql)
{
    __shared__ float hs[4][HCOLS];
    __shared__ float ph[4][49];   // 0..15 phi_k, 16..31 phi_q, 32..47 phi_ltm, 48 gate
    const int tid = threadIdx.x;
    const int w = tid >> 6;
    const int lane = tid & 63;
    const int t = blockIdx.x * 4 + w;

    for (int i = lane; i < HCOLS; i += 64) hs[w][i] = H[t * HCOLS + i];
    __syncthreads();

    float val = 0.0f;
    if (lane < 16) {
        float a = ke_b2[lane];
        for (int k = 0; k < 256; ++k) a += hs[w][k] * ke_w2[k * 16 + lane];
        val = tanhf(a) * PI_F;
    } else if (lane < 32) {
        int o = lane - 16;
        float a = qe_b2[o];
        for (int k = 0; k < 256; ++k) a += hs[w][256 + k] * qe_w2[k * 16 + o];
        val = tanhf(a) * PI_F;
    } else if (lane < 48) {
        int o = lane - 32;
        float a = lke_b2[o];
        for (int k = 0; k < 256; ++k) a += hs[w][512 + k] * lke_w2[k * 16 + o];
        val = tanhf(a) * PI_F;
    } else if (lane == 48) {
        float a = gate_b2[0];
        for (int k = 0; k < 128; ++k) a += hs[w][768 + k] * gate_w2[k];
        val = sigmoidf_(a);
    }
    if (lane < 49) ph[w][lane] = val;
    __syncthreads();

    float sw[4];
    {
        float s0 = set_weights[0], s1 = set_weights[1], s2 = set_weights[2], s3 = set_weights[3];
        float mx = fmaxf(fmaxf(s0, s1), fmaxf(s2, s3));
        float e0 = expf(s0 - mx), e1 = expf(s1 - mx), e2 = expf(s2 - mx), e3 = expf(s3 - mx);
        float inv = 1.0f / (e0 + e1 + e2 + e3);
        sw[0] = e0 * inv; sw[1] = e1 * inv; sw[2] = e2 * inv; sw[3] = e3 * inv;
    }
    const float g = ph[w][48];
    const float aq = g * 0.2f;                                  // gate / (N_SETS+1)
    const float apos = (1.0f - g) * sigmoidf_(pos_weight[0]);
    const float altm = sigmoidf_(ltm_weight[0]) / sqrtf(fmaxf(ltm_count[0], 1.0f) * 16.0f);
    const int l = t & (LL - 1);
    float* fkr  = Fk  + t * FDIM;
    float* fqr  = Fq  + t * FDIM;
    float* fqlr = Fql + t * 32;

    if (lane < 16) {
        int p = lane;
        float sk, ck; sincosf(ph[w][p], &sk, &ck);
        fkr[2 * p] = ck; fkr[2 * p + 1] = sk;
        float sq, cq; sincosf(ph[w][16 + p], &sq, &cq);
        float wq = aq * sw[p >> 2];
        fqr[2 * p] = wq * cq; fqr[2 * p + 1] = wq * sq;
        float sl, cl; sincosf(ph[w][32 + p], &sl, &cl);
        fqlr[2 * p] = altm * cl; fqlr[2 * p + 1] = altm * sl;
        float th = (float)l * pos_freqs[p] * (2.0f * PI_F);
        float sp, cp; sincosf(th, &sp, &cp);
        fkr[40 + 2 * p] = cp; fkr[41 + 2 * p] = sp;
        fqr[40 + 2 * p] = apos * cp; fqr[41 + 2 * p] = apos * sp;
    } else if (lane < 20) {
        int p = lane - 16;
        float pjk = ph[w][p] + ph[w][p + 4] + ph[w][p + 8] + ph[w][p + 12];
        float pjq = ph[w][16 + p] + ph[w][20 + p] + ph[w][24 + p] + ph[w][28 + p];
        float sjk, cjk; sincosf(pjk, &sjk, &cjk);
        float sjq, cjq; sincosf(pjq, &sjq, &cjq);
        fkr[32 + 2 * p] = cjk; fkr[33 + 2 * p] = sjk;
        fqr[32 + 2 * p] = aq * cjq; fqr[33 + 2 * p] = aq * sjq;
    } else if (lane < 24) {
        int p = lane - 20;
        fkr[72 + 2 * p] = 0.0f; fkr[73 + 2 * p] = 0.0f;
        fqr[72 + 2 * p] = 0.0f; fqr[73 + 2 * p] = 0.0f;
    }
}

// ---------------- K3: exclusive scan of joint-key phasors -> write gate -> scale Fk[0..39]
__global__ __launch_bounds__(512) void k3_scan(
    float* __restrict__ Fk,
    const float* __restrict__ resonance_scale, const float* __restrict__ resonance_threshold,
    const float* __restrict__ surprise_scale, const float* __restrict__ surprise_bias)
{
    __shared__ float km[8][LL];
    const int b = blockIdx.x;
    const int tid = threadIdx.x;
    const int w = tid >> 6;     // series: 32 + w in Fk dims (2p+comp)
    const int lane = tid & 63;
    {
        float v[32];
        float s = 0.0f;
        const float* src = Fk + (size_t)(b * LL) * FDIM + 32 + w;
        int l0 = lane * 32;
        #pragma unroll 4
        for (int i = 0; i < 32; ++i) { v[i] = src[(size_t)(l0 + i) * FDIM]; s += v[i]; }
        float local = s;
        #pragma unroll
        for (int off = 1; off < 64; off <<= 1) {
            float n = __shfl_up(s, off);
            if (lane >= off) s += n;
        }
        float run = s - local;   // exclusive base
        #pragma unroll 4
        for (int i = 0; i < 32; ++i) { km[w][l0 + i] = run; run += v[i]; }
    }
    __syncthreads();
    const float sc  = fminf(fmaxf(resonance_scale[0], 1.0f), 20.0f);
    const float th  = fminf(fmaxf(resonance_threshold[0], 0.1f), 0.9f);
    const float ssc = surprise_scale[0];
    const float sbi = surprise_bias[0];
    for (int q = 0; q < 4; ++q) {
        int l = tid + 512 * q;
        float rm = 0.0f;
        #pragma unroll
        for (int p = 0; p < 4; ++p) {
            float re = km[2 * p][l], im = km[2 * p + 1][l];
            rm += sqrtf(re * re + im * im);
        }
        rm *= 0.25f;
        float nr = rm / sqrtf(fmaxf((float)l, 1.0f));
        float sur = 0.5f * (1.0f - tanhf(sc * (nr - th)));
        float wg = sigmoidf_(ssc * (sur - 0.5f) + sbi);
        float4* row = reinterpret_cast<float4*>(Fk + (size_t)(b * LL + l) * FDIM);
        #pragma unroll
        for (int j = 0; j < 10; ++j) {   // dims 0..39 (bank+joint); pos dims untouched
            float4 vv = row[j];
            vv.x *= wg; vv.y *= wg; vv.z *= wg; vv.w *= wg;
            row[j] = vv;
        }
    }
}

// ---------------- K4a: per-chunk key state S_c = F_k_c^T @ V_c   (80 x 256)
__global__ __launch_bounds__(256) void k4a_state(
    const float* __restrict__ Fk, const float* __restrict__ V, float* __restrict__ S)
{
    __shared__ __align__(16) float fk[CC][FPAD];
    const int c = blockIdx.x;
    const int f0 = blockIdx.y * 20;       // f quarter: 20 floats = 80B, 16B-aligned
    const int tid = threadIdx.x;          // = output dim d
    for (int i = tid; i < CC * FDIM; i += 256) {
        int r = i / FDIM, cx = i - r * FDIM;
        fk[r][cx] = Fk[(size_t)c * CC * FDIM + i];
    }
    __syncthreads();
    float acc[20];
    #pragma unroll
    for (int f = 0; f < 20; ++f) acc[f] = 0.0f;
    const float* vp = V + (size_t)c * CC * DD + tid;
    for (int r = 0; r < CC; ++r) {
        float v = vp[(size_t)r * DD];
        #pragma unroll
        for (int g = 0; g < 5; ++g) {
            float4 q = *reinterpret_cast<const float4*>(&fk[r][f0 + 4 * g]);
            acc[4 * g + 0] += q.x * v; acc[4 * g + 1] += q.y * v;
            acc[4 * g + 2] += q.z * v; acc[4 * g + 3] += q.w * v;
        }
    }
    float* sp = S + (size_t)c * SST + tid;
    #pragma unroll
    for (int f = 0; f < 20; ++f) sp[(size_t)(f0 + f) * DD] = acc[f];
}

// ---------------- K4b: exclusive prefix-sum of chunk states within each batch
__global__ __launch_bounds__(256) void k4b_scan(
    const float* __restrict__ S, float* __restrict__ M)
{
    const int e = blockIdx.x * 256 + threadIdx.x;   // element in [0, SST)
    const int b = blockIdx.y;
    float run = 0.0f;
    for (int cc = 0; cc < NCB; ++cc) {
        size_t o = ((size_t)(b * NCB + cc)) * SST + e;
        M[o] = run;
        run += S[o];
    }
}

// ---------------- K4c: out_c = F_q_c @ M_prev[c] + tril(F_q_c F_k_c^T) @ V_c + LTM
__global__ __launch_bounds__(256) void k4c_out(
    const float* __restrict__ Fq, const float* __restrict__ Fk,
    const float* __restrict__ Fql, const float* __restrict__ V,
    const float* __restrict__ M, const float* __restrict__ ltm_mem,
    float* __restrict__ Tot)
{
    __shared__ __align__(16) float fq[CC][FPAD];
    __shared__ __align__(16) float fk[CC][FPAD];
    __shared__ __align__(16) float sc[CC][68];    // 68*4=272B rows, 16B aligned
    const int c = blockIdx.x;
    const int tid = threadIdx.x;
    for (int i = tid; i < CC * FDIM; i += 256) {
        int r = i / FDIM, cx = i - r * FDIM;
        fq[r][cx] = Fq[(size_t)c * CC * FDIM + i];
        fk[r][cx] = Fk[(size_t)c * CC * FDIM + i];
    }
    __syncthreads();
    // dense 64x64 score tile; masked (i<j) entries written as zero
    #pragma unroll
    for (int q = 0; q < 16; ++q) {
        int idx = tid + 256 * q;
        int i = idx >> 6, j = idx & 63;     // i uniform per wave, j = lane
        float s = 0.0f;
        if (i >= j) {
            #pragma unroll
            for (int g = 0; g < 20; ++g) {
                float4 a = *reinterpret_cast<const float4*>(&fq[i][4 * g]);
                float4 b = *reinterpret_cast<const float4*>(&fk[j][4 * g]);
                s += a.x * b.x + a.y * b.y + a.z * b.z + a.w * b.w;
            }
        }
        sc[i][j] = s;
    }
    __syncthreads();
    const int d = tid;
    float acc[CC];
    #pragma unroll
    for (int i = 0; i < CC; ++i) acc[i] = 0.0f;
    // inter-chunk part: F_q @ M_prev
    const float* mp = M + (size_t)c * SST + d;
    #pragma unroll 1
    for (int g = 0; g < 20; ++g) {
        float m0 = mp[(size_t)(4 * g + 0) * DD];
        float m1 = mp[(size_t)(4 * g + 1) * DD];
        float m2 = mp[(size_t)(4 * g + 2) * DD];
        float m3 = mp[(size_t)(4 * g + 3) * DD];
        #pragma unroll
        for (int i = 0; i < CC; ++i) {
            float4 a = *reinterpret_cast<const float4*>(&fq[i][4 * g]);
            acc[i] += a.x * m0 + a.y * m1 + a.z * m2 + a.w * m3;
        }
    }
    // intra-chunk part: scores @ V  (masked entries are zero)
    const float* vp = V + (size_t)c * CC * DD + d;
    #pragma unroll 1
    for (int j4 = 0; j4 < 16; ++j4) {
        float v0 = vp[(size_t)(4 * j4 + 0) * DD];
        float v1 = vp[(size_t)(4 * j4 + 1) * DD];
        float v2 = vp[(size_t)(4 * j4 + 2) * DD];
        float v3 = vp[(size_t)(4 * j4 + 3) * DD];
        #pragma unroll
        for (int i = 0; i < CC; ++i) {
            float4 s4 = *reinterpret_cast<const float4*>(&sc[i][4 * j4]);
            acc[i] += s4.x * v0 + s4.y * v1 + s4.z * v2 + s4.w * v3;
        }
    }
    // LTM epilogue: stage Fql chunk rows into fk buffer (done with scores/fk)
    __syncthreads();
    for (int i = tid; i < CC * 32; i += 256) {
        int r = i >> 5, p = i & 31;
        fk[r][p] = Fql[(size_t)(c * CC + r) * 32 + p];
    }
    float mre[16], mim[16];
    #pragma unroll
    for (int p = 0; p < 16; ++p) {
        mre[p] = ltm_mem[((size_t)p * DD + d) * 2];
        mim[p] = ltm_mem[((size_t)p * DD + d) * 2 + 1];
    }
    __syncthreads();
    float* tp = Tot + (size_t)c * CC * DD + d;
    #pragma unroll 1
    for (int i = 0; i < CC; ++i) {
        float a = acc[i];
        #pragma unroll
        for (int p = 0; p < 16; ++p)
            a += fk[i][2 * p] * mre[p] + fk[i][2 * p + 1] * mim[p];
        tp[(size_t)i * DD] = a;
    }
}

// ---------------- K5: LayerNorm + output projection
__global__ __launch_bounds__(256) void k5_out(
    const float* __restrict__ Tot,
    const float* __restrict__ gln, const float* __restrict__ bln,
    const float* __restrict__ out_w, const float* __restrict__ out_b,
    float* __restrict__ out)
{
    __shared__ float hsn[8][DD];
    const int tid = threadIdx.x;
    const int t0 = blockIdx.x * 8;
    const int w = tid >> 6, lane = tid & 63;
    {
        int r = 2 * w + (lane >> 5);
        int l5 = lane & 31;
        float vbuf[8];
        float s = 0.0f, s2 = 0.0f;
        #pragma unroll
        for (int i = 0; i < 8; ++i) {
            float v = Tot[(size_t)(t0 + r) * DD + l5 * 8 + i];
            vbuf[i] = v; s += v; s2 += v * v;
        }
        #pragma unroll
        for (int off = 1; off < 32; off <<= 1) {
            s  += __shfl_xor(s, off);
            s2 += __shfl_xor(s2, off);
        }
        float mu = s * (1.0f / 256.0f);
        float var = s2 * (1.0f / 256.0f) - mu * mu;
        float rstd = rsqrtf(var + 1e-5f);
        #pragma unroll
        for (int i = 0; i < 8; ++i) {
            int k = l5 * 8 + i;
            hsn[r][k] = (vbuf[i] - mu) * rstd * gln[k] + bln[k];
        }
    }
    __syncthreads();
    float acc[8];
    #pragma unroll
    for (int t = 0; t < 8; ++t) acc[t] = 0.0f;
    for (int k = 0; k < DD; ++k) {
        float wv = out_w[k * DD + tid];
        #pragma unroll
        for (int t = 0; t < 8; ++t) acc[t] += hsn[t][k] * wv;
    }
    float ob = out_b[tid];
    #pragma unroll
    for (int t = 0; t < 8; ++t)
        out[(size_t)(t0 + t) * DD + tid] = acc[t] + ob;
}

extern "C" void kernel_launch(void* const* d_in, const int* in_sizes, int n_in,
                              void* d_out, int out_size, void* d_ws, size_t ws_size,
                              hipStream_t stream)
{
    (void)in_sizes; (void)n_in; (void)out_size; (void)ws_size;
    const float* x        = (const float*)d_in[0];
    const float* ke_w1    = (const float*)d_in[1];
    const float* ke_b1    = (const float*)d_in[2];
    const float* ke_w2    = (const float*)d_in[3];
    const float* ke_b2    = (const float*)d_in[4];
    const float* qe_w1    = (const float*)d_in[5];
    const float* qe_b1    = (const float*)d_in[6];
    const float* qe_w2    = (const float*)d_in[7];
    const float* qe_b2    = (const float*)d_in[8];
    const float* v_w      = (const float*)d_in[9];
    const float* v_b      = (const float*)d_in[10];
    const float* out_ln_g = (const float*)d_in[11];
    const float* out_ln_b = (const float*)d_in[12];
    const float* out_w    = (const float*)d_in[13];
    const float* out_b    = (const float*)d_in[14];
    const float* set_weights = (const float*)d_in[15];
    const float* pos_weight  = (const float*)d_in[16];
    const float* gate_w1  = (const float*)d_in[17];
    const float* gate_b1  = (const float*)d_in[18];
    const float* gate_w2  = (const float*)d_in[19];
    const float* gate_b2  = (const float*)d_in[20];
    const float* lke_w1   = (const float*)d_in[21];
    const float* lke_b1   = (const float*)d_in[22];
    const float* lke_w2   = (const float*)d_in[23];
    const float* lke_b2   = (const float*)d_in[24];
    const float* surprise_scale      = (const float*)d_in[25];
    const float* surprise_bias       = (const float*)d_in[26];
    const float* resonance_scale     = (const float*)d_in[27];
    const float* resonance_threshold = (const float*)d_in[28];
    const float* ltm_weight = (const float*)d_in[29];
    const float* pos_freqs  = (const float*)d_in[30];
    const float* ltm_mem    = (const float*)d_in[31];  // complex64 interleaved (16,256)
    const float* ltm_count  = (const float*)d_in[32];

    float* ws  = (float*)d_ws;
    float* H   = ws;                    // NT*896 floats
    float* V   = H   + (size_t)NT * HCOLS;
    float* Fk  = V   + (size_t)NT * DD;
    float* Fq  = Fk  + (size_t)NT * FDIM;
    float* Fql = Fq  + (size_t)NT * FDIM;
    float* Tot = Fql + (size_t)NT * 32;
    // chunk states alias H (H is dead after k2; NC*SST*2 = 2.62M floats < NT*896 = 3.67M)
    float* S   = H;
    float* M   = H + (size_t)NC * SST;

    k1_first<<<NT / 8, 256, 0, stream>>>(x, ke_w1, ke_b1, qe_w1, qe_b1, lke_w1, lke_b1,
                                         gate_w1, gate_b1, v_w, v_b, H, V);
    k2_second<<<NT / 4, 256, 0, stream>>>(H, ke_w2, ke_b2, qe_w2, qe_b2, lke_w2, lke_b2,
                                          gate_w2, gate_b2, set_weights, pos_weight,
                                          ltm_weight, ltm_count, pos_freqs, Fk, Fq, Fql);
    k3_scan<<<BB, 512, 0, stream>>>(Fk, resonance_scale, resonance_threshold,
                                    surprise_scale, surprise_bias);
    k4a_state<<<dim3(NC, 4), 256, 0, stream>>>(Fk, V, S);
    k4b_scan<<<dim3(SST / 256, BB), 256, 0, stream>>>(S, M);
    k4c_out<<<NC, 256, 0, stream>>>(Fq, Fk, Fql, V, M, ltm_mem, Tot);
    k5_out<<<NT / 8, 256, 0, stream>>>(Tot, out_ln_g, out_ln_b, out_w, out_b, (float*)d_out);
}